// Round 7
// baseline (554.494 us; speedup 1.0000x reference)
//
#include <hip/hip_runtime.h>

// B=64, H=W=512, K=7, VALID conv -> 506x506.
#define HW     512
#define OW     506
#define S      73          // LDS stride (dwords): odd, ==1 mod 4 -> all-32-bank spread
#define TCOLS  64          // output cols per block (16 col-groups x 4)
#define TROWS  48          // output rows per block (4 waves x 4 rowgroups x 3)
#define IROWS  54          // staged input rows (48 + 6)
#define NDW    (IROWS * S) // 3942 dwords = 15768 B -> 8+ blocks/CU by LDS

// (256,8): VGPR cap 64 -> 8 waves/SIMD (m69: waves halve at vgpr=64).
// Natural demand ~45 (acc12+win10+addr) -> safely under cap, no spill.
__global__ __launch_bounds__(256, 8) void conv7x7_v7(
    const float* __restrict__ in,      // [64][512][512]
    const float* __restrict__ weight,  // [7][7]
    const float* __restrict__ bias,    // [1]
    float* __restrict__ out)           // [64][506][506]
{
    __shared__ float tile[NDW];

    const int tid = threadIdx.x;
    const int x0  = blockIdx.x * TCOLS;
    const int y0  = blockIdx.y * TROWS;
    const int b   = blockIdx.z;
    const float* __restrict__ inb = in + (size_t)b * (HW * HW);

    // ---- weights + bias -> SGPRs (uniform) ----
    float wv[49];
#pragma unroll
    for (int i = 0; i < 49; ++i)
        wv[i] = __uint_as_float(__builtin_amdgcn_readfirstlane(__float_as_uint(weight[i])));
    const float bv = __uint_as_float(__builtin_amdgcn_readfirstlane(__float_as_uint(bias[0])));

    // ---- stage 54 x 70 tile at stride 73 ----
    // ds_write_b32 at consecutive dwords (2 lanes/bank = free, m136).
    // Global side: ~coalesced 4B/lane. Pad cols 70..72 never touched.
#pragma unroll
    for (int k = 0; k < 16; ++k) {
        const int q = tid + k * 256;
        if (q < NDW) {
            const int r = q / S;            // const-divide -> magic mul
            const int c = q - r * S;
            if (c < 70) {
                const int gy = min(y0 + r, HW - 1);
                const int gx = min(x0 + c, HW - 1);
                tile[q] = inb[gy * HW + gx];
            }
        }
    }
    __syncthreads();

    // ---- thread -> 3 rows x 4 cols micro-tile ----
    // lane = 16a + c16. Read addr (fixed ir,j): 219a + 4*c16 (+wave-uniform).
    // 219a mod 32 = {0,27,22,17}: covers all residues mod 4; 4*c16 covers
    // multiples of 4 twice -> all 32 banks x exactly 2 lanes = free (m136).
    const int lane = tid & 63;
    const int w    = tid >> 6;
    const int a    = lane >> 4;            // row-group 0..3
    const int c16  = lane & 15;            // col-group 0..15
    const int r0   = w * 12 + a * 3;       // first output row (block-local)
    const int cb   = 4 * c16;              // first output col (block-local)

    float acc[12];
#pragma unroll
    for (int i = 0; i < 12; ++i) acc[i] = 0.f;

    const float* rp = tile + r0 * S + cb;

    // 9 input rows, each read once (10 x ds_read_b32, immediate offsets);
    // scatter into 3 output-row slots. All indices compile-time.
#pragma unroll
    for (int ir = 0; ir < 9; ++ir) {
        float win[10];
#pragma unroll
        for (int j = 0; j < 10; ++j) win[j] = rp[ir * S + j];

#pragma unroll
        for (int kr = 0; kr < 7; ++kr) {
            const int s = ir - kr;          // compile-time after unroll
            if (s >= 0 && s < 3) {
#pragma unroll
                for (int kc = 0; kc < 7; ++kc) {
                    const float wk = wv[kr * 7 + kc];
#pragma unroll
                    for (int j = 0; j < 4; ++j)
                        acc[s * 4 + j] = fmaf(wk, win[kc + j], acc[s * 4 + j]);
                }
            }
        }
    }

    // ---- store 3 rows x 4 cols as float2 pairs ----
    const int ox0 = x0 + cb;               // even; OW even -> pairs never straddle
    float* __restrict__ outb = out + (size_t)b * (OW * OW);
#pragma unroll
    for (int s = 0; s < 3; ++s) {
        const int oy = y0 + r0 + s;
        if (oy < OW) {
            float* orow = outb + (size_t)oy * OW + ox0;
#pragma unroll
            for (int p = 0; p < 2; ++p) {
                if (ox0 + 2 * p + 1 < OW) {
                    *reinterpret_cast<float2*>(orow + 2 * p) =
                        make_float2(acc[s * 4 + 2 * p] + bv,
                                    acc[s * 4 + 2 * p + 1] + bv);
                }
            }
        }
    }
}

extern "C" void kernel_launch(void* const* d_in, const int* in_sizes, int n_in,
                              void* d_out, int out_size, void* d_ws, size_t ws_size,
                              hipStream_t stream) {
    const float* enc_x  = (const float*)d_in[0];
    const float* weight = (const float*)d_in[1];
    const float* bias   = (const float*)d_in[2];
    float* outp         = (float*)d_out;

    dim3 grid(8, 11, 64);   // 8x64 cols, 11x48 rows (covers 506), 64 images
    dim3 block(256);
    hipLaunchKernelGGL(conv7x7_v7, grid, block, 0, stream,
                       enc_x, weight, bias, outp);
}

// Round 8
// 40.831 us; speedup vs baseline: 13.5803x; 13.5803x over previous
//
#include <hip/hip_runtime.h>

// B=64, H=W=512, K=7, VALID conv -> 506x506.
// v8: LDS-free direct convolution. Input (67MB) fits L3; a wave's 7 shifted
// row reads have 7x L1 line reuse -> staging through LDS (v0-v7) bought
// nothing and cost barriers + bank conflicts + occupancy. No launch_bounds
// cap (2nd arg caused catastrophic spills in v3/v4/v7).
#define HW 512
#define OW 506

__global__ __launch_bounds__(256) void conv7x7_v8(
    const float* __restrict__ in,      // [64][512][512]
    const float* __restrict__ weight,  // [7][7]
    const float* __restrict__ bias,    // [1]
    float* __restrict__ out)           // [64][506][506]
{
    const int tid  = threadIdx.x;
    const int lane = tid & 63;
    const int w    = tid >> 6;
    const int x0   = blockIdx.x * 64;
    const int yb   = blockIdx.y * 32 + w * 8;   // this wave's first output row
    const int b    = blockIdx.z;

    // ---- weights + bias -> SGPRs (uniform, statically indexed) ----
    float wv[49];
#pragma unroll
    for (int i = 0; i < 49; ++i)
        wv[i] = __uint_as_float(__builtin_amdgcn_readfirstlane(__float_as_uint(weight[i])));
    const float bv = __uint_as_float(__builtin_amdgcn_readfirstlane(__float_as_uint(bias[0])));

    const float* __restrict__ ib = in + (size_t)b * (HW * HW);

    // lane -> output column; clamp so x+6 <= 511 stays in-row (clamped lanes
    // compute garbage but never store: ox guard below).
    const int x = min(x0 + lane, OW - 1);

    float acc[8];
#pragma unroll
    for (int i = 0; i < 8; ++i) acc[i] = 0.f;

    // 14 input rows feed 8 output rows; each row: 7 coalesced global loads
    // (lane i -> consecutive addrs; kc folds into immediate offsets, L1 hits),
    // then guarded static scatter of 49 FMAs.
#pragma unroll
    for (int ir = 0; ir < 14; ++ir) {
        const int row = min(yb + ir, HW - 1);   // wave-uniform
        const float* p = ib + row * HW + x;
        float win[7];
#pragma unroll
        for (int kc = 0; kc < 7; ++kc) win[kc] = p[kc];

#pragma unroll
        for (int kr = 0; kr < 7; ++kr) {
            const int s = ir - kr;              // compile-time after unroll
            if (s >= 0 && s < 8) {
#pragma unroll
                for (int kc = 0; kc < 7; ++kc)
                    acc[s] = fmaf(wv[kr * 7 + kc], win[kc], acc[s]);
            }
        }
    }

    // ---- store: 64 lanes = 256B contiguous per output row ----
    const int ox = x0 + lane;
    if (ox < OW) {
        float* __restrict__ outb = out + (size_t)b * (OW * OW);
#pragma unroll
        for (int s = 0; s < 8; ++s) {
            const int oy = yb + s;
            if (oy < OW) outb[(size_t)oy * OW + ox] = acc[s] + bv;
        }
    }
}

extern "C" void kernel_launch(void* const* d_in, const int* in_sizes, int n_in,
                              void* d_out, int out_size, void* d_ws, size_t ws_size,
                              hipStream_t stream) {
    const float* enc_x  = (const float*)d_in[0];
    const float* weight = (const float*)d_in[1];
    const float* bias   = (const float*)d_in[2];
    float* outp         = (float*)d_out;

    dim3 grid(8, 16, 64);   // 64 cols x 32 rows per block (4 waves x 8 rows), 64 images
    dim3 block(256);
    hipLaunchKernelGGL(conv7x7_v8, grid, block, 0, stream,
                       enc_x, weight, bias, outp);
}